// Round 1
// baseline (398.181 us; speedup 1.0000x reference)
//
#include <hip/hip_runtime.h>
#include <hip/hip_bf16.h>
#include <math.h>

#define S_LEN 2048
#define HID_DIM 2048
#define NH 16
#define NKV 4
#define HD 128

typedef __attribute__((ext_vector_type(8))) short bf16x8;
typedef __attribute__((ext_vector_type(4))) float f32x4;

__device__ inline unsigned short f2bf(float f) {
  unsigned int u = __float_as_uint(f);
  unsigned int r = u + 0x7FFFu + ((u >> 16) & 1u);
  return (unsigned short)(r >> 16);
}

// ---------------- hidden f32 -> bf16 ----------------
__global__ __launch_bounds__(256) void f32_to_bf16_kernel(
    const float* __restrict__ x, unsigned short* __restrict__ y, int n)
{
  int i = (blockIdx.x * 256 + threadIdx.x) * 4;
  if (i < n) {
    float4 v = *(const float4*)&x[i];
    ushort4 o;
    o.x = f2bf(v.x); o.y = f2bf(v.y); o.z = f2bf(v.z); o.w = f2bf(v.w);
    *(ushort4*)&y[i] = o;
  }
}

// ---------------- W [K][N] f32 -> W^T [N][K] bf16 ----------------
__global__ __launch_bounds__(256) void transpose_bf16_kernel(
    const float* __restrict__ W, unsigned short* __restrict__ Wt, int K, int N)
{
  __shared__ float t[32][33];
  int bx = blockIdx.x * 32;  // N dim
  int by = blockIdx.y * 32;  // K dim
  int tx = threadIdx.x, ty = threadIdx.y;
  #pragma unroll
  for (int i = 0; i < 32; i += 8)
    t[ty + i][tx] = W[(size_t)(by + ty + i) * N + bx + tx];
  __syncthreads();
  #pragma unroll
  for (int i = 0; i < 32; i += 8)
    Wt[(size_t)(bx + ty + i) * K + by + tx] = f2bf(t[tx][ty + i]);
}

// ---------------- GEMM: C[M][N] f32 = A[M][K]bf16 * B^T[N][K]bf16 ----------------
#define BM 64
#define BN 64
#define BK 32
#define LDT 40  // padded LDS stride (bf16 elems), 80B rows -> 16B aligned, 2-way banks (free)

__global__ __launch_bounds__(256) void gemm_bt(
    const unsigned short* __restrict__ A,
    const unsigned short* __restrict__ Bt,
    float* __restrict__ C, int M, int N, int K)
{
  __shared__ __align__(16) unsigned short As[BM * LDT];
  __shared__ __align__(16) unsigned short Bs[BN * LDT];
  int bm = blockIdx.y * BM;
  int bn = blockIdx.x * BN;
  int tid = threadIdx.x;
  int lane = tid & 63, wave = tid >> 6;
  int lcol = lane & 15, lquad = lane >> 4;

  f32x4 zero = {0.f, 0.f, 0.f, 0.f};
  f32x4 acc[4];
  #pragma unroll
  for (int i = 0; i < 4; i++) acc[i] = zero;

  int srow = tid >> 2;            // 0..63
  int skseg = (tid & 3) * 8;      // 0,8,16,24

  for (int k0 = 0; k0 < K; k0 += BK) {
    *(uint4*)&As[srow * LDT + skseg] = *(const uint4*)&A[(size_t)(bm + srow) * K + k0 + skseg];
    *(uint4*)&Bs[srow * LDT + skseg] = *(const uint4*)&Bt[(size_t)(bn + srow) * K + k0 + skseg];
    __syncthreads();
    bf16x8 af = *(const bf16x8*)&As[(wave * 16 + lcol) * LDT + lquad * 8];
    #pragma unroll
    for (int nb = 0; nb < 4; nb++) {
      bf16x8 bfv = *(const bf16x8*)&Bs[(nb * 16 + lcol) * LDT + lquad * 8];
      acc[nb] = __builtin_amdgcn_mfma_f32_16x16x32_bf16(af, bfv, acc[nb], 0, 0, 0);
    }
    __syncthreads();
  }
  #pragma unroll
  for (int nb = 0; nb < 4; nb++)
    #pragma unroll
    for (int r = 0; r < 4; r++) {
      int mm = bm + wave * 16 + lquad * 4 + r;
      int nn = bn + nb * 16 + lcol;
      C[(size_t)mm * N + nn] = acc[nb][r];
    }
}

// ---------------- RoPE: qkv_raw f32 -> q_ws/k_ws bf16, outk f32 (repeated) ----------------
__global__ __launch_bounds__(256) void rope_kernel(
    const float* __restrict__ qkv_raw,   // [S][3072]
    const int* __restrict__ positions,
    unsigned short* __restrict__ q_ws,   // [NH][S][HD]
    unsigned short* __restrict__ k_ws,   // [NKV][S][HD]
    float* __restrict__ outk)            // [NH][S][HD]
{
  int s = blockIdx.x;
  float pos = (float)positions[s];
  const float* row = &qkv_raw[(size_t)s * 3072];
  for (int t = threadIdx.x; t < 20 * 64; t += 256) {
    int ch = t >> 6, j = t & 63;
    float freq = expf(-(float)j * 0.14391156831212787f);  // ln(10000)/64
    float ang = pos * freq;
    float sn, c;
    sincosf(ang, &sn, &c);
    if (ch < NH) {
      float x1 = row[ch * HD + j], x2 = row[ch * HD + j + 64];
      float o1 = x1 * c - x2 * sn;
      float o2 = x1 * sn + x2 * c;
      size_t base = ((size_t)ch * S_LEN + s) * HD;
      q_ws[base + j] = f2bf(o1);
      q_ws[base + j + 64] = f2bf(o2);
    } else {
      int kv = ch - NH;
      float x1 = row[2048 + kv * HD + j], x2 = row[2048 + kv * HD + j + 64];
      float o1 = x1 * c - x2 * sn;
      float o2 = x1 * sn + x2 * c;
      size_t kbase = ((size_t)kv * S_LEN + s) * HD;
      k_ws[kbase + j] = f2bf(o1);
      k_ws[kbase + j + 64] = f2bf(o2);
      #pragma unroll
      for (int g = 0; g < 4; g++) {
        size_t ob = ((size_t)(kv * 4 + g) * S_LEN + s) * HD;
        outk[ob + j] = o1;
        outk[ob + j + 64] = o2;
      }
    }
  }
}

// ---------------- V prep: repeated V f32 out + V^T bf16 ----------------
__global__ __launch_bounds__(256) void prep_v_kernel(
    const float* __restrict__ qkv_raw,   // [S][3072], V at col 2560
    float* __restrict__ outv,            // [NH][S][HD]
    unsigned short* __restrict__ vT)     // [NKV][HD][S]
{
  __shared__ float t[32][33];
  int s0 = blockIdx.x * 32, d0 = blockIdx.y * 32, kv = blockIdx.z;
  int tx = threadIdx.x, ty = threadIdx.y;
  #pragma unroll
  for (int i = 0; i < 32; i += 8)
    t[ty + i][tx] = qkv_raw[(size_t)(s0 + ty + i) * 3072 + 2560 + kv * HD + d0 + tx];
  __syncthreads();
  #pragma unroll
  for (int i = 0; i < 32; i += 8) {
    float val = t[ty + i][tx];
    #pragma unroll
    for (int g = 0; g < 4; g++)
      outv[((size_t)(kv * 4 + g) * S_LEN + s0 + ty + i) * HD + d0 + tx] = val;
  }
  #pragma unroll
  for (int i = 0; i < 32; i += 8)
    vT[((size_t)kv * HD + d0 + ty + i) * S_LEN + s0 + tx] = f2bf(t[tx][ty + i]);
}

// ---------------- Flash attention ----------------
// grid (S/64, NH), 256 threads (4 waves x 16 q-rows)
#define KLD 136  // K-tile LDS stride (272B, 16-aligned)
#define VLD 72   // V^T / P LDS stride (144B, 16-aligned)

__global__ __launch_bounds__(256) void flash_attn(
    const unsigned short* __restrict__ q_ws,   // [NH][S][HD]
    const unsigned short* __restrict__ k_ws,   // [NKV][S][HD]
    const unsigned short* __restrict__ vT_ws,  // [NKV][HD][S]
    unsigned short* __restrict__ attn_ws)      // [S][NH*HD]
{
  __shared__ __align__(16) unsigned short Ks[64 * KLD];
  __shared__ __align__(16) unsigned short Vs[128 * VLD];
  __shared__ __align__(16) unsigned short Ps[4][16 * VLD];
  int qt = blockIdx.x, h = blockIdx.y, kvh = h >> 2;
  int tid = threadIdx.x, lane = tid & 63, wave = tid >> 6;
  int lquad = lane >> 4, lcol = lane & 15;

  bf16x8 qf[4];
  {
    const unsigned short* qp =
        &q_ws[((size_t)h * S_LEN + qt * 64 + wave * 16 + lcol) * HD + lquad * 8];
    #pragma unroll
    for (int st = 0; st < 4; st++) qf[st] = *(const bf16x8*)&qp[st * 32];
  }
  f32x4 zero = {0.f, 0.f, 0.f, 0.f};
  f32x4 o_acc[8];
  #pragma unroll
  for (int i = 0; i < 8; i++) o_acc[i] = zero;
  float m_run[4], l_run[4];
  #pragma unroll
  for (int r = 0; r < 4; r++) { m_run[r] = -1e30f; l_run[r] = 0.f; }

  const float scale = 0.08838834764831845f;  // 1/sqrt(128)

  for (int kt = 0; kt <= qt; kt++) {
    #pragma unroll
    for (int it = 0; it < 4; it++) {
      int id = tid + it * 256;
      int krow = id >> 4, seg = (id & 15) * 8;
      *(uint4*)&Ks[krow * KLD + seg] =
          *(const uint4*)&k_ws[((size_t)kvh * S_LEN + kt * 64 + krow) * HD + seg];
    }
    #pragma unroll
    for (int it = 0; it < 4; it++) {
      int id = tid + it * 256;
      int drow = id >> 3, seg = (id & 7) * 8;
      *(uint4*)&Vs[drow * VLD + seg] =
          *(const uint4*)&vT_ws[((size_t)kvh * HD + drow) * S_LEN + kt * 64 + seg];
    }
    __syncthreads();

    // scores: S = Q K^T  (16 q-rows x 64 keys per wave)
    f32x4 sc[4];
    #pragma unroll
    for (int nb = 0; nb < 4; nb++) {
      sc[nb] = zero;
      #pragma unroll
      for (int st = 0; st < 4; st++) {
        bf16x8 kf = *(const bf16x8*)&Ks[(nb * 16 + lcol) * KLD + st * 32 + lquad * 8];
        sc[nb] = __builtin_amdgcn_mfma_f32_16x16x32_bf16(qf[st], kf, sc[nb], 0, 0, 0);
      }
    }

    // online softmax (row = qt*64 + wave*16 + lquad*4 + r lives in 16-lane group lquad)
    int qrow_base = qt * 64 + wave * 16 + lquad * 4;
    int kcol_base = kt * 64;
    float pvals[4][4];
    #pragma unroll
    for (int r = 0; r < 4; r++) {
      float mx = -1e30f;
      #pragma unroll
      for (int nb = 0; nb < 4; nb++) {
        float sv = sc[nb][r] * scale;
        int kc = kcol_base + nb * 16 + lcol;
        if (kc > qrow_base + r) sv = -1e30f;
        pvals[nb][r] = sv;
        mx = fmaxf(mx, sv);
      }
      #pragma unroll
      for (int m = 1; m < 16; m <<= 1) mx = fmaxf(mx, __shfl_xor(mx, m, 16));
      float mnew = fmaxf(m_run[r], mx);
      float alpha = __expf(m_run[r] - mnew);
      m_run[r] = mnew;
      float ls = 0.f;
      #pragma unroll
      for (int nb = 0; nb < 4; nb++) {
        float p = __expf(pvals[nb][r] - mnew);
        pvals[nb][r] = p;
        ls += p;
      }
      #pragma unroll
      for (int m = 1; m < 16; m <<= 1) ls += __shfl_xor(ls, m, 16);
      l_run[r] = l_run[r] * alpha + ls;
      #pragma unroll
      for (int ob = 0; ob < 8; ob++) o_acc[ob][r] *= alpha;
    }

    // P: C-layout -> LDS -> A-layout (wave-private region, no cross-wave hazard)
    unsigned short* myPs = &Ps[wave][0];
    #pragma unroll
    for (int r = 0; r < 4; r++)
      #pragma unroll
      for (int nb = 0; nb < 4; nb++)
        myPs[(lquad * 4 + r) * VLD + nb * 16 + lcol] = f2bf(pvals[nb][r]);
    asm volatile("s_waitcnt lgkmcnt(0)" ::: "memory");

    bf16x8 pa0 = *(const bf16x8*)&myPs[lcol * VLD + lquad * 8];
    bf16x8 pa1 = *(const bf16x8*)&myPs[lcol * VLD + 32 + lquad * 8];
    #pragma unroll
    for (int ob = 0; ob < 8; ob++) {
      bf16x8 v0 = *(const bf16x8*)&Vs[(ob * 16 + lcol) * VLD + lquad * 8];
      bf16x8 v1 = *(const bf16x8*)&Vs[(ob * 16 + lcol) * VLD + 32 + lquad * 8];
      o_acc[ob] = __builtin_amdgcn_mfma_f32_16x16x32_bf16(pa0, v0, o_acc[ob], 0, 0, 0);
      o_acc[ob] = __builtin_amdgcn_mfma_f32_16x16x32_bf16(pa1, v1, o_acc[ob], 0, 0, 0);
    }
    __syncthreads();
  }

  #pragma unroll
  for (int r = 0; r < 4; r++) {
    float inv_l = 1.f / l_run[r];
    int row = qt * 64 + wave * 16 + lquad * 4 + r;
    #pragma unroll
    for (int ob = 0; ob < 8; ob++)
      attn_ws[(size_t)row * (NH * HD) + h * HD + ob * 16 + lcol] =
          f2bf(o_acc[ob][r] * inv_l);
  }
}

// ---------------- launch ----------------
extern "C" void kernel_launch(void* const* d_in, const int* in_sizes, int n_in,
                              void* d_out, int out_size, void* d_ws, size_t ws_size,
                              hipStream_t stream)
{
  const float* hidden    = (const float*)d_in[0];
  const int*   positions = (const int*)d_in[1];
  // d_in[2] = mask (causal triu(-1e9)) — implemented analytically
  const float* Wq = (const float*)d_in[3];
  const float* Wk = (const float*)d_in[4];
  const float* Wv = (const float*)d_in[5];
  const float* Wo = (const float*)d_in[6];

  float* out  = (float*)d_out;                       // [S][HID]
  float* outk = out + (size_t)S_LEN * HID_DIM;       // [NH][S][HD]
  float* outv = outk + (size_t)NH * S_LEN * HD;      // [NH][S][HD]

  char* ws = (char*)d_ws;
  unsigned short* h_bf   = (unsigned short*)(ws);                        // 8MB  [S][HID] bf16
  unsigned short* WT     = (unsigned short*)(ws + ((size_t)8  << 20));   // 12MB [3072][2048] bf16 (Wq^T|Wk^T|Wv^T)
  unsigned short* WoT    = (unsigned short*)(ws + ((size_t)20 << 20));   // 8MB  [2048][2048] bf16
  float*          qkvraw = (float*)         (ws + ((size_t)28 << 20));   // 24MB [S][3072] f32
  unsigned short* q_ws   = (unsigned short*)(ws + ((size_t)52 << 20));   // 8MB  [NH][S][HD] bf16
  unsigned short* k_ws   = (unsigned short*)(ws + ((size_t)60 << 20));   // 2MB  [NKV][S][HD] bf16
  unsigned short* vT_ws  = (unsigned short*)(ws + ((size_t)62 << 20));   // 2MB  [NKV][HD][S] bf16
  unsigned short* attn   = (unsigned short*)(ws + ((size_t)64 << 20));   // 8MB  [S][NH*HD] bf16
  // total 72MB of workspace

  dim3 tb(32, 8);
  f32_to_bf16_kernel<<<4096, 256, 0, stream>>>(hidden, h_bf, S_LEN * HID_DIM);
  transpose_bf16_kernel<<<dim3(64, 64), tb, 0, stream>>>(Wq, WT, HID_DIM, 2048);
  transpose_bf16_kernel<<<dim3(16, 64), tb, 0, stream>>>(Wk, WT + (size_t)2048 * 2048, HID_DIM, 512);
  transpose_bf16_kernel<<<dim3(16, 64), tb, 0, stream>>>(Wv, WT + (size_t)2560 * 2048, HID_DIM, 512);
  transpose_bf16_kernel<<<dim3(64, 64), tb, 0, stream>>>(Wo, WoT, 2048, 2048);

  gemm_bt<<<dim3(48, 32), 256, 0, stream>>>(h_bf, WT, qkvraw, 2048, 3072, 2048);

  rope_kernel<<<2048, 256, 0, stream>>>(qkvraw, positions, q_ws, k_ws, outk);
  prep_v_kernel<<<dim3(64, 4, 4), tb, 0, stream>>>(qkvraw, outv, vT_ws);

  flash_attn<<<dim3(32, 16), 256, 0, stream>>>(q_ws, k_ws, vT_ws, attn);

  gemm_bt<<<dim3(32, 32), 256, 0, stream>>>(attn, WoT, out, 2048, 2048, 2048);
}